// Round 11
// baseline (15.313 us; speedup 1.0000x reference)
//
#include <hip/hip_runtime.h>

#define NPTS 512
#define DIM  128
#define MARGIN 0.5f
#define CNT_EPS 1e-8f
#define NBLK 256            // 2 anchors per block, 1 block per CU

__device__ __forceinline__ float dot4(float4 a, float4 b) {
    return a.x * b.x + a.y * b.y + a.z * b.z + a.w * b.w;
}

// ---------------------------------------------------------------------------
// SINGLE-NODE version of r10. Compute body identical (1024 thr, 2 anchors
// per block, 8 lanes/row, register-shared b-loads, 4 waves/SIMD).
// Fence-free cross-block finalize:
//   - block publishes partial via atomicExch (device-scope RMW -> executes
//     at the coherent point; NO cache maintenance, unlike __threadfence/
//     grid.sync which cost +18/+35 us in r2/r7)
//   - s_waitcnt vmcnt(0): exchs complete before the ticket RMW (wave-local)
//   - ticket = monotone counter in d_ws; winner is the block whose returned
//     old satisfies old%256==255 -> exactly one winner for ANY initial
//     value (poison-proof, no memset node, no state reset needed; counter
//     grows across calls but output is identical every call)
//   - winner's wave 0 re-reads all 256 partials via bitwise atomicAdd(p,0)
//     (coherent-point reads), fixed-order reduce, writes out[0].
// Deadlock-free: no spin, no co-residency assumption.
// ---------------------------------------------------------------------------
__global__ __launch_bounds__(1024, 4)
void triplet_onepass_kernel(const float* __restrict__ x,
                            const int* __restrict__ labels,
                            unsigned int* __restrict__ psum_bits,
                            unsigned int* __restrict__ pcnt,
                            unsigned int* __restrict__ ticket,
                            float* __restrict__ out) {
    __shared__ float drow[2][NPTS];   // distance rows for the 2 anchors
    __shared__ float posv[2][NPTS];
    __shared__ int   lab[NPTS];
    __shared__ int   npos_sh[2];
    __shared__ float wsum[16];
    __shared__ int   wcnt[16];

    const int tid = threadIdx.x;     // 0..1023
    const int w   = tid >> 6;        // wave 0..15
    const int l   = tid & 63;        // lane
    const int g   = l >> 3;          // row-group 0..7 within wave
    const int c   = l & 7;           // column slot 0..7 within group

    const int i0 = 2 * blockIdx.x;
    const int i1 = i0 + 1;

    if (tid < NPTS) lab[tid] = labels[tid];
    if (tid < 2)    npos_sh[tid] = 0;
    const int li0 = labels[i0];
    const int li1 = labels[i1];

    // both anchors' fragments in registers: columns c+8*it (it=0..3)
    const float4* xi0 = (const float4*)(x + i0 * DIM);
    const float4* xi1 = (const float4*)(x + i1 * DIM);
    float4 xf0[4], xf1[4];
#pragma unroll
    for (int it = 0; it < 4; ++it) xf0[it] = xi0[c + 8 * it];
#pragma unroll
    for (int it = 0; it < 4; ++it) xf1[it] = xi1[c + 8 * it];

    // squared norms: per-lane partial, 8-lane butterfly
    float sq0 = 0.f, sq1 = 0.f;
#pragma unroll
    for (int it = 0; it < 4; ++it) {
        sq0 += dot4(xf0[it], xf0[it]);
        sq1 += dot4(xf1[it], xf1[it]);
    }
    sq0 += __shfl_xor(sq0, 1, 64);
    sq0 += __shfl_xor(sq0, 2, 64);
    sq0 += __shfl_xor(sq0, 4, 64);
    sq1 += __shfl_xor(sq1, 1, 64);
    sq1 += __shfl_xor(sq1, 2, 64);
    sq1 += __shfl_xor(sq1, 4, 64);

    // distance rows: pass p covers rows p*128 + w*8 + g; ONE b-load feeds
    // dp0, dp1 and sp (register-level sharing, per-CU traffic at floor).
#pragma unroll 2
    for (int pass = 0; pass < 4; ++pass) {
        const int j = pass * 128 + w * 8 + g;
        const float4* xj4 = (const float4*)(x + j * DIM);
        float dp0 = 0.f, dp1 = 0.f, sp = 0.f;
#pragma unroll
        for (int it = 0; it < 4; ++it) {
            float4 b = xj4[c + 8 * it];
            dp0 += dot4(b, xf0[it]);
            dp1 += dot4(b, xf1[it]);
            sp  += dot4(b, b);
        }
        dp0 += __shfl_xor(dp0, 1, 64);
        dp0 += __shfl_xor(dp0, 2, 64);
        dp0 += __shfl_xor(dp0, 4, 64);
        dp1 += __shfl_xor(dp1, 1, 64);
        dp1 += __shfl_xor(dp1, 2, 64);
        dp1 += __shfl_xor(dp1, 4, 64);
        sp  += __shfl_xor(sp, 1, 64);
        sp  += __shfl_xor(sp, 2, 64);
        sp  += __shfl_xor(sp, 4, 64);
        if (c == 0) {
            float dsq0 = sq0 + sp - 2.f * dp0;
            float dsq1 = sq1 + sp - 2.f * dp1;
            dsq0 = dsq0 > 0.f ? dsq0 : 0.f;
            dsq1 = dsq1 > 0.f ? dsq1 : 0.f;
            // reference's zero-mask only affects exact-zero entries (the
            // diagonal), excluded by validity -> plain sqrt exact here.
            drow[0][j] = (dsq0 == 0.f) ? 0.f : sqrtf(dsq0);
            drow[1][j] = (dsq1 == 0.f) ? 0.f : sqrtf(dsq1);
        }
    }
    __syncthreads();

    // compaction + pair loop: half h owns anchor i_h, thread handles k=t
    const int h = tid >> 9;          // 0 or 1
    const int t = tid & 511;
    const int lih = h ? li1 : li0;
    const int ih  = h ? i1 : i0;

    if (lab[t] == lih && t != ih) {
        int p = atomicAdd(&npos_sh[h], 1);
        posv[h][p] = drow[h][t] + MARGIN;
    }
    __syncthreads();
    const int npos = npos_sh[h];

    const bool  isneg = (lab[t] != lih);
    const float dk    = drow[h][t];
    float lsum = 0.f;
    int   lcnt = 0;
    for (int p = 0; p < npos; ++p) {
        float v = posv[h][p] - dk;       // d_ij - d_ik + margin
        if (isneg && v > 0.f) {
            lsum += v;
            lcnt += (v > CNT_EPS) ? 1 : 0;
        }
    }

    // per-wave shuffle reduce, then 16-partial combine (both anchors summed)
#pragma unroll
    for (int off = 1; off < 64; off <<= 1) {
        lsum += __shfl_xor(lsum, off, 64);
        lcnt += __shfl_xor(lcnt, off, 64);
    }
    if (l == 0) { wsum[w] = lsum; wcnt[w] = lcnt; }
    __syncthreads();

    // ---- fence-free publish + ticket ----
    int win = 0;
    if (tid == 0) {
        float s = 0.f;
        int   cc = 0;
#pragma unroll
        for (int q = 0; q < 16; ++q) { s += wsum[q]; cc += wcnt[q]; }
        unsigned int op = atomicExch(&psum_bits[blockIdx.x],
                                     __float_as_uint(s));
        unsigned int oc = atomicExch(&pcnt[blockIdx.x], (unsigned int)cc);
        asm volatile("" :: "v"(op), "v"(oc));            // keep returns live
        asm volatile("s_waitcnt vmcnt(0)" ::: "memory"); // exchs at coherent pt
        unsigned int old = atomicAdd(ticket, 1u);
        win = ((old & (NBLK - 1u)) == (NBLK - 1u)) ? 1 : 0;  // 256th arrival
    }

    if (tid < 64) {
        win = __shfl(win, 0, 64);        // broadcast within wave 0
        if (win) {
            // winner: all 256 partials are complete at the coherent point;
            // read them via bitwise add-0 RMWs (coherent reads), fixed order.
            float s = 0.f;
            unsigned int cc = 0;
#pragma unroll
            for (int u = 0; u < 4; ++u) {
                int q = tid + 64 * u;
                s  += __uint_as_float(atomicAdd(&psum_bits[q], 0u));
                cc += atomicAdd(&pcnt[q], 0u);
            }
#pragma unroll
            for (int off = 1; off < 64; off <<= 1) {
                s  += __shfl_xor(s, off, 64);
                cc += __shfl_xor(cc, off, 64);
            }
            if (tid == 0) out[0] = s / (float)cc;
        }
    }
}

extern "C" void kernel_launch(void* const* d_in, const int* in_sizes, int n_in,
                              void* d_out, int out_size, void* d_ws, size_t ws_size,
                              hipStream_t stream) {
    const float* x      = (const float*)d_in[0];   // [512,128] fp32
    const int*   labels = (const int*)d_in[1];     // [512] int32
    float*       out    = (float*)d_out;           // scalar fp32

    unsigned int* psum_bits = (unsigned int*)d_ws;        // 256 (exch'd each call)
    unsigned int* pcnt      = psum_bits + NBLK;           // 256 (exch'd each call)
    unsigned int* ticket    = pcnt + NBLK;                // monotone, poison-proof

    triplet_onepass_kernel<<<NBLK, 1024, 0, stream>>>(x, labels, psum_bits,
                                                      pcnt, ticket, out);
}

// Round 12
// 14.502 us; speedup vs baseline: 1.0560x; 1.0560x over previous
//
#include <hip/hip_runtime.h>

#define NPTS 512
#define DIM  128
#define MARGIN 0.5f
#define CNT_EPS 1e-8f
#define NBLK 256            // 2 anchors per block, 1 block per CU

__device__ __forceinline__ float dot4(float4 a, float4 b) {
    return a.x * b.x + a.y * b.y + a.z * b.z + a.w * b.w;
}

// ---------------------------------------------------------------------------
// r10 structure (best: 14.28 us) + micro-opts:
//   - pass loop FULLY unrolled: all 16 global float4 loads issue up-front,
//     L2 latency overlaps the FMA/butterfly stream
//   - lab[] LDS mirror dropped (labels[] reads are L1-broadcast-cached)
// One block (1024 thr = 16 waves) per 2 anchors, grid 256 = 1 block/CU,
// 4 waves/SIMD. 8 lanes/row, one b-load feeds dp0/dp1/sp (per-CU L1
// traffic at the 256 KB floor). Tail: half-per-anchor compaction + pair
// loop, wave shuffle reduce, 16-partial combine, plain store; 64-thread
// finalize node (graph nodes pipeline launch overhead - r11 showed the
// fused atomic tail is slower).
// ---------------------------------------------------------------------------
__global__ __launch_bounds__(1024, 4)
void triplet_row_kernel(const float* __restrict__ x,
                        const int* __restrict__ labels,
                        float* __restrict__ psum,
                        int* __restrict__ pcnt) {
    __shared__ float drow[2][NPTS];   // distance rows for the 2 anchors
    __shared__ float posv[2][NPTS];
    __shared__ int   npos_sh[2];
    __shared__ float wsum[16];
    __shared__ int   wcnt[16];

    const int tid = threadIdx.x;     // 0..1023
    const int w   = tid >> 6;        // wave 0..15
    const int l   = tid & 63;        // lane
    const int g   = l >> 3;          // row-group 0..7 within wave
    const int c   = l & 7;           // column slot 0..7 within group

    const int i0 = 2 * blockIdx.x;
    const int i1 = i0 + 1;

    if (tid < 2) npos_sh[tid] = 0;
    const int li0 = labels[i0];
    const int li1 = labels[i1];

    // both anchors' fragments in registers: columns c+8*it (it=0..3)
    const float4* xi0 = (const float4*)(x + i0 * DIM);
    const float4* xi1 = (const float4*)(x + i1 * DIM);
    float4 xf0[4], xf1[4];
#pragma unroll
    for (int it = 0; it < 4; ++it) xf0[it] = xi0[c + 8 * it];
#pragma unroll
    for (int it = 0; it < 4; ++it) xf1[it] = xi1[c + 8 * it];

    // squared norms: per-lane partial, 8-lane butterfly
    float sq0 = 0.f, sq1 = 0.f;
#pragma unroll
    for (int it = 0; it < 4; ++it) {
        sq0 += dot4(xf0[it], xf0[it]);
        sq1 += dot4(xf1[it], xf1[it]);
    }
    sq0 += __shfl_xor(sq0, 1, 64);
    sq0 += __shfl_xor(sq0, 2, 64);
    sq0 += __shfl_xor(sq0, 4, 64);
    sq1 += __shfl_xor(sq1, 1, 64);
    sq1 += __shfl_xor(sq1, 2, 64);
    sq1 += __shfl_xor(sq1, 4, 64);

    // distance rows: pass p covers rows p*128 + w*8 + g; ONE b-load feeds
    // dp0, dp1 and sp. FULL unroll -> all 16 loads issue early (ILP).
#pragma unroll
    for (int pass = 0; pass < 4; ++pass) {
        const int j = pass * 128 + w * 8 + g;
        const float4* xj4 = (const float4*)(x + j * DIM);
        float dp0 = 0.f, dp1 = 0.f, sp = 0.f;
#pragma unroll
        for (int it = 0; it < 4; ++it) {
            float4 b = xj4[c + 8 * it];
            dp0 += dot4(b, xf0[it]);
            dp1 += dot4(b, xf1[it]);
            sp  += dot4(b, b);
        }
        dp0 += __shfl_xor(dp0, 1, 64);
        dp0 += __shfl_xor(dp0, 2, 64);
        dp0 += __shfl_xor(dp0, 4, 64);
        dp1 += __shfl_xor(dp1, 1, 64);
        dp1 += __shfl_xor(dp1, 2, 64);
        dp1 += __shfl_xor(dp1, 4, 64);
        sp  += __shfl_xor(sp, 1, 64);
        sp  += __shfl_xor(sp, 2, 64);
        sp  += __shfl_xor(sp, 4, 64);
        if (c == 0) {
            float dsq0 = sq0 + sp - 2.f * dp0;
            float dsq1 = sq1 + sp - 2.f * dp1;
            dsq0 = dsq0 > 0.f ? dsq0 : 0.f;
            dsq1 = dsq1 > 0.f ? dsq1 : 0.f;
            // reference's zero-mask only affects exact-zero entries (the
            // diagonal), excluded by validity -> plain sqrt exact here.
            drow[0][j] = (dsq0 == 0.f) ? 0.f : sqrtf(dsq0);
            drow[1][j] = (dsq1 == 0.f) ? 0.f : sqrtf(dsq1);
        }
    }
    __syncthreads();

    // compaction + pair loop: half h owns anchor i_h, thread handles k=t
    const int h = tid >> 9;          // 0 or 1
    const int t = tid & 511;
    const int lih = h ? li1 : li0;
    const int ih  = h ? i1 : i0;
    const int lt  = labels[t];       // L1-broadcast-cached

    if (lt == lih && t != ih) {
        int p = atomicAdd(&npos_sh[h], 1);
        posv[h][p] = drow[h][t] + MARGIN;
    }
    __syncthreads();
    const int npos = npos_sh[h];

    const bool  isneg = (lt != lih);
    const float dk    = drow[h][t];
    float lsum = 0.f;
    int   lcnt = 0;
    for (int p = 0; p < npos; ++p) {
        float v = posv[h][p] - dk;       // d_ij - d_ik + margin
        if (isneg && v > 0.f) {
            lsum += v;
            lcnt += (v > CNT_EPS) ? 1 : 0;
        }
    }

    // per-wave shuffle reduce, then 16-partial combine (both anchors summed)
#pragma unroll
    for (int off = 1; off < 64; off <<= 1) {
        lsum += __shfl_xor(lsum, off, 64);
        lcnt += __shfl_xor(lcnt, off, 64);
    }
    if (l == 0) { wsum[w] = lsum; wcnt[w] = lcnt; }
    __syncthreads();
    if (tid == 0) {
        float s = 0.f;
        int   cc = 0;
#pragma unroll
        for (int q = 0; q < 16; ++q) { s += wsum[q]; cc += wcnt[q]; }
        psum[blockIdx.x] = s;            // plain stores; kernel-boundary
        pcnt[blockIdx.x] = cc;           // coherence is runtime-managed
    }
}

// ---------------------------------------------------------------------------
// Finalize: ONE wave, one float4/int4 per lane, shuffle reduce, no LDS.
// ---------------------------------------------------------------------------
__global__ void finalize_kernel(const float4* __restrict__ psum4,
                                const int4* __restrict__ pcnt4,
                                float* __restrict__ out) {
    const int t = threadIdx.x;           // 0..63 ; 64*4 = 256 partials
    float4 a  = psum4[t];
    int4   ca = pcnt4[t];
    float s  = a.x + a.y + a.z + a.w;
    int   cc = ca.x + ca.y + ca.z + ca.w;
#pragma unroll
    for (int off = 1; off < 64; off <<= 1) {
        s  += __shfl_xor(s, off, 64);
        cc += __shfl_xor(cc, off, 64);
    }
    if (t == 0) out[0] = s / (float)cc;
}

extern "C" void kernel_launch(void* const* d_in, const int* in_sizes, int n_in,
                              void* d_out, int out_size, void* d_ws, size_t ws_size,
                              hipStream_t stream) {
    const float* x      = (const float*)d_in[0];   // [512,128] fp32
    const int*   labels = (const int*)d_in[1];     // [512] int32
    float*       out    = (float*)d_out;           // scalar fp32

    float* psum = (float*)d_ws;          // 256 floats (fully overwritten)
    int*   pcnt = (int*)(psum + NBLK);   // 256 ints  (fully overwritten)

    triplet_row_kernel<<<NBLK, 1024, 0, stream>>>(x, labels, psum, pcnt);
    finalize_kernel<<<1, 64, 0, stream>>>((const float4*)psum,
                                          (const int4*)pcnt, out);
}